// Round 8
// baseline (125.198 us; speedup 1.0000x reference)
//
#include <hip/hip_runtime.h>

// MyEncoder: B=8, S=4096, E=128, D=24, fp32 in/out.
// out = softmax((xWq+bq)(xWk+bk)^T / sqrt(128)) (xWv+bv) Wo + bo
// bf16-MFMA pipeline: prep -> proj (QKV GEMM) -> attn (flash partials,
// K-split, transposed scores, in-register P, full-K PV, MFMA-computed l,
// 2 query-tiles per wave) -> combine (sum partials + wO epilogue).
// Softmax without max-subtraction (scores tiny, shift-invariant) => K-split
// partials purely additive. exp2 with log2(e) folded into Q scale.
//
// attn math (per 32-key group c2, keys permuted at staging):
//   chunk e=2*c2:   S^T[key=c2*32+quad*8+r][q=col]   = mfma(A=K_e, B=Q)
//   chunk o=2*c2+1: S^T[key=c2*32+quad*8+4+r][q=col] = mfma(A=K_o, B=Q)
//   P (exp2 of both) packs into ONE full B-frag (k=quad*8+j, j=0..7 real)
//   O^T += mfma(A=V^T natural, B=P)   ; V row d=24 staged as 1.0 => Ot1's
//   d=24 element is l (sum of P).
// Two q-tiles per wave share the same K/V fragment reads: 8 MFMA per
// 4 ds_read_b128 (was 4:4) and half the staging/barriers per query.

#define B_ 8
#define S_ 4096
#define E_ 128
#define D_ 24
#define N_ (B_ * S_)               // 32768 rows
#define SCALE 0.08838834764831845f // 1/sqrt(128)
#define LOG2E 1.4426950408889634f

#define TK 128                     // keys per LDS tile in attn
#define KS_STRIDE 40               // K_s row stride (shorts)
#define VS_STRIDE 136              // V_s row stride (shorts): 128 + 8 pad
#define HS_STRIDE 40               // H_s row stride in combine
#define XS_STRIDE 136              // x_s row stride (bf16) in proj
#define OS_STRIDE 84               // out_s row stride (fp32) in proj

typedef __attribute__((ext_vector_type(8))) short bfrag;   // 8 bf16 = 4 VGPR
typedef __attribute__((ext_vector_type(4))) float ffrag;   // 4 fp32 acc

__device__ inline unsigned short f2bf(float f) {           // RNE fp32->bf16
    unsigned int x = __builtin_bit_cast(unsigned int, f);
    return (unsigned short)((x + 0x7fffu + ((x >> 16) & 1u)) >> 16);
}
__device__ inline unsigned int pack2(float a, float b) {
    return (unsigned int)f2bf(a) | ((unsigned int)f2bf(b) << 16);
}
// round-half-up bf16 pair pack: 2 int-adds + v_perm (validated r5 on HW)
__device__ inline unsigned int pack2h(float a, float b) {
    unsigned int ua = __builtin_bit_cast(unsigned int, a) + 0x8000u;
    unsigned int ub = __builtin_bit_cast(unsigned int, b) + 0x8000u;
    return __builtin_amdgcn_perm(ub, ua, 0x07060302);      // [a.hi16 | b.hi16]
}

// ---------------- Kernel 0: weight prep (8 blocks) ----------------
__global__ __launch_bounds__(256) void prep_kernel(
    const float* __restrict__ wQ, const float* __restrict__ bQ,
    const float* __restrict__ wK, const float* __restrict__ bK,
    const float* __restrict__ wV, const float* __restrict__ bV,
    const float* __restrict__ wO,
    unsigned short* __restrict__ Wf, unsigned short* __restrict__ wOf,
    float* __restrict__ bqkv)
{
    const int gtid   = blockIdx.x * 256 + threadIdx.x;
    const int stride = gridDim.x * 256;
    const float qs = SCALE * LOG2E;
    for (int idx = gtid; idx < 4 * 5 * 512; idx += stride) {
        const int j    = idx & 7;
        const int lane = (idx >> 3) & 63;
        const int nt   = (idx >> 9) % 5;
        const int kt   = idx / 2560;
        const int n = nt * 16 + (lane & 15);
        const int k = kt * 32 + ((lane >> 4) << 3) + j;
        float v = 0.0f;
        if (n < 24)      v = wQ[k * 24 + n] * qs;
        else if (n < 48) v = wK[k * 24 + (n - 24)];
        else if (n < 72) v = wV[k * 24 + (n - 48)];
        Wf[idx] = f2bf(v);
    }
    for (int idx = gtid; idx < 8 * 512; idx += stride) {
        const int j    = idx & 7;
        const int lane = (idx >> 3) & 63;
        const int nt   = idx >> 9;
        const int k = ((lane >> 4) << 3) + j;
        const int e = nt * 16 + (lane & 15);
        wOf[idx] = (k < 24) ? f2bf(wO[k * 128 + e]) : (unsigned short)0;
    }
    if (gtid < 80) {
        float v = 0.0f;
        if (gtid < 24)      v = bQ[gtid] * qs;
        else if (gtid < 48) v = bK[gtid - 24];
        else if (gtid < 72) v = bV[gtid - 48];
        bqkv[gtid] = v;
    }
}

// ---------------- Kernel 1: QKV projection (MFMA) ----------------
__global__ __launch_bounds__(256) void proj_kernel(
    const float* __restrict__ x, const unsigned short* __restrict__ Wf,
    const float* __restrict__ bqkv,
    unsigned short* __restrict__ Qbf, unsigned short* __restrict__ Kbf,
    unsigned short* __restrict__ Vt)
{
    __shared__ float smem[64 * OS_STRIDE];          // 21504 B, dual-purpose
    unsigned short* xs = (unsigned short*)smem;     // [64][XS_STRIDE]
    float* os = smem;                               // [64][OS_STRIDE]

    const int tid  = threadIdx.x;
    const int lane = tid & 63;
    const int w    = tid >> 6;
    const int col  = lane & 15;
    const int quad = lane >> 4;
    const int rb   = blockIdx.x * 64;

    #pragma unroll
    for (int i = 0; i < 8; ++i) {
        const int idx = i * 256 + tid;
        const int row = idx >> 5, c4 = idx & 31;
        const float4 xv = *(const float4*)(x + (size_t)(rb + row) * 128 + c4 * 4);
        uint2 h;
        h.x = pack2(xv.x, xv.y);
        h.y = pack2(xv.z, xv.w);
        *(uint2*)(&xs[row * XS_STRIDE + c4 * 4]) = h;
    }

    bfrag Wfr[20];
    #pragma unroll
    for (int f = 0; f < 20; ++f)
        Wfr[f] = *(const bfrag*)(Wf + (f * 64 + lane) * 8);

    __syncthreads();

    ffrag acc[5];
    #pragma unroll
    for (int nt = 0; nt < 5; ++nt) acc[nt] = (ffrag){0.f, 0.f, 0.f, 0.f};

    #pragma unroll
    for (int kt = 0; kt < 4; ++kt) {
        const bfrag Af = *(const bfrag*)(&xs[(w * 16 + col) * XS_STRIDE + kt * 32 + quad * 8]);
        #pragma unroll
        for (int nt = 0; nt < 5; ++nt)
            acc[nt] = __builtin_amdgcn_mfma_f32_16x16x32_bf16(Af, Wfr[kt * 5 + nt], acc[nt], 0, 0, 0);
    }

    __syncthreads();

    #pragma unroll
    for (int nt = 0; nt < 5; ++nt) {
        const float bb = bqkv[nt * 16 + col];
        #pragma unroll
        for (int r = 0; r < 4; ++r)
            os[(w * 16 + quad * 4 + r) * OS_STRIDE + nt * 16 + col] = acc[nt][r] + bb;
    }
    __syncthreads();

    // Q (tid<128) / K (tid>=128): row-major bf16, cols padded to 32
    {
        const int half  = tid & 1;
        const int row   = (tid >> 1) & 63;
        const int isK   = tid >> 7;
        const int cbase = isK * 24;
        unsigned int pk[8];
        #pragma unroll
        for (int g = 0; g < 8; ++g) {
            const int c0 = half * 16 + g * 2;
            const float f0 = (c0     < 24) ? os[row * OS_STRIDE + cbase + c0]     : 0.0f;
            const float f1 = (c0 + 1 < 24) ? os[row * OS_STRIDE + cbase + c0 + 1] : 0.0f;
            pk[g] = pack2(f0, f1);
        }
        unsigned short* dst = (isK ? Kbf : Qbf) + (size_t)(rb + row) * 32 + half * 16;
        *(uint4*)(dst)     = make_uint4(pk[0], pk[1], pk[2], pk[3]);
        *(uint4*)(dst + 8) = make_uint4(pk[4], pk[5], pk[6], pk[7]);
    }

    // Vt: transposed [b][d][s], 16B stores
    if (tid < 192) {
        const int d  = tid % 24;
        const int ch = tid / 24;
        unsigned int p[4];
        #pragma unroll
        for (int g = 0; g < 4; ++g) {
            const float f0 = os[(ch * 8 + g * 2 + 0) * OS_STRIDE + 48 + d];
            const float f1 = os[(ch * 8 + g * 2 + 1) * OS_STRIDE + 48 + d];
            p[g] = pack2(f0, f1);
        }
        const int b = rb >> 12, s0 = rb & 4095;
        uint4* dst = (uint4*)(Vt + (((size_t)(b * 24 + d)) << 12) + s0 + ch * 8);
        *dst = make_uint4(p[0], p[1], p[2], p[3]);
    }
}

// ---------------- Kernel 2: flash attention partials ----------------
// Grid (N/128, KSP). 128 queries/block: 4 waves x 2 q-tiles of 16.
// K staged permuted: key k -> row (k&~31)+(((k>>2)&1)<<4)+(((k&31)>>3)<<2)+(k&3)
// so chunk 2*c2 gives keys quad*8+r, chunk 2*c2+1 gives quad*8+4+r -> one
// full K=32 P fragment per 32 keys. V natural order; V row d=24 = 1.0 so
// the PV MFMA computes l in Ot1's d=24 element. Both q-tiles reuse the
// same K/V fragment reads.
__global__ __launch_bounds__(256, 4) void attn_kernel(
    const unsigned short* __restrict__ Qbf, const unsigned short* __restrict__ Kbf,
    const unsigned short* __restrict__ Vt,
    float* __restrict__ Opart, float* __restrict__ lpart)
{
    __shared__ unsigned short Ks[TK * KS_STRIDE];     // 10240 B
    __shared__ unsigned short Vs[32 * VS_STRIDE];     // 8704 B (rows 25-31 unused)

    const int tid    = threadIdx.x;
    const int lane   = tid & 63;
    const int w      = tid >> 6;
    const int col    = lane & 15;
    const int quad   = lane >> 4;
    const int blk    = blockIdx.x;                    // 0..N/128-1
    const int split  = blockIdx.y;
    const int nsp    = gridDim.y;
    const int kchunk = S_ / nsp;
    const int b      = blk >> 5;                      // 32 blocks per batch
    const int qbase0 = blk * 128 + w * 16;
    const int qbase1 = qbase0 + 64;

    // ones row d=24 (written once; staging only touches rows 0..23)
    if (tid < 16)
        *(uint4*)(&Vs[24 * VS_STRIDE + tid * 8]) =
            make_uint4(0x3F803F80u, 0x3F803F80u, 0x3F803F80u, 0x3F803F80u);

    const bfrag Qf0 = *(const bfrag*)(Qbf + (size_t)(qbase0 + col) * 32 + quad * 8);
    const bfrag Qf1 = *(const bfrag*)(Qbf + (size_t)(qbase1 + col) * 32 + quad * 8);

    ffrag Ot00 = {0.f, 0.f, 0.f, 0.f};   // tile0: O^T d = quad*4+r      (0..15)
    ffrag Ot10 = {0.f, 0.f, 0.f, 0.f};   // tile0: O^T d = 16+quad*4+r   (d=24 is l)
    ffrag Ot01 = {0.f, 0.f, 0.f, 0.f};   // tile1 low
    ffrag Ot11 = {0.f, 0.f, 0.f, 0.f};   // tile1 high

    const unsigned short* Kbase = Kbf + ((size_t)(b * 4096) + split * kchunk) * 32;
    const unsigned short* Vbase = Vt + (size_t)(b * 24) * 4096 + split * kchunk;

    __syncthreads();   // ones row visible

    for (int kb = 0; kb < kchunk; kb += TK) {
        // K tile: permuted rows, 128 keys x 32 bf16
        #pragma unroll
        for (int i = 0; i < 2; ++i) {
            const int idx = i * 256 + tid;            // 0..511
            const int key = idx >> 2, ch = idx & 3;
            const uint4 t4 = *(const uint4*)(Kbase + (size_t)(kb + key) * 32 + ch * 8);
            const int row = (key & ~31) + (((key >> 2) & 1) << 4)
                          + (((key & 31) >> 3) << 2) + (key & 3);
            *(uint4*)(&Ks[row * KS_STRIDE + ch * 8]) = t4;
        }
        // V tile: 24 d-rows x 128 keys, natural order
        #pragma unroll
        for (int i = 0; i < 2; ++i) {
            const int u = i * 256 + tid;
            if (u < 384) {
                const int d = u >> 4, ch = u & 15;
                const uint4 t4 = *(const uint4*)(Vbase + (size_t)d * 4096 + kb + ch * 8);
                *(uint4*)(&Vs[d * VS_STRIDE + ch * 8]) = t4;
            }
        }
        __syncthreads();

        #pragma unroll
        for (int c2 = 0; c2 < 4; ++c2) {
            const bfrag Kfe = *(const bfrag*)(&Ks[(c2 * 32 + col) * KS_STRIDE + quad * 8]);
            const bfrag Kfo = *(const bfrag*)(&Ks[(c2 * 32 + 16 + col) * KS_STRIDE + quad * 8]);
            ffrag Se0 = {0.f, 0.f, 0.f, 0.f};
            ffrag So0 = {0.f, 0.f, 0.f, 0.f};
            ffrag Se1 = {0.f, 0.f, 0.f, 0.f};
            ffrag So1 = {0.f, 0.f, 0.f, 0.f};
            Se0 = __builtin_amdgcn_mfma_f32_16x16x32_bf16(Kfe, Qf0, Se0, 0, 0, 0);
            So0 = __builtin_amdgcn_mfma_f32_16x16x32_bf16(Kfo, Qf0, So0, 0, 0, 0);
            Se1 = __builtin_amdgcn_mfma_f32_16x16x32_bf16(Kfe, Qf1, Se1, 0, 0, 0);
            So1 = __builtin_amdgcn_mfma_f32_16x16x32_bf16(Kfo, Qf1, So1, 0, 0, 0);

            union { bfrag f; unsigned int u[4]; } P0, P1;
            P0.u[0] = pack2h(__builtin_amdgcn_exp2f(Se0[0]), __builtin_amdgcn_exp2f(Se0[1]));
            P0.u[1] = pack2h(__builtin_amdgcn_exp2f(Se0[2]), __builtin_amdgcn_exp2f(Se0[3]));
            P0.u[2] = pack2h(__builtin_amdgcn_exp2f(So0[0]), __builtin_amdgcn_exp2f(So0[1]));
            P0.u[3] = pack2h(__builtin_amdgcn_exp2f(So0[2]), __builtin_amdgcn_exp2f(So0[3]));
            P1.u[0] = pack2h(__builtin_amdgcn_exp2f(Se1[0]), __builtin_amdgcn_exp2f(Se1[1]));
            P1.u[1] = pack2h(__builtin_amdgcn_exp2f(Se1[2]), __builtin_amdgcn_exp2f(Se1[3]));
            P1.u[2] = pack2h(__builtin_amdgcn_exp2f(So1[0]), __builtin_amdgcn_exp2f(So1[1]));
            P1.u[3] = pack2h(__builtin_amdgcn_exp2f(So1[2]), __builtin_amdgcn_exp2f(So1[3]));

            const bfrag Va0 = *(const bfrag*)(&Vs[col * VS_STRIDE + c2 * 32 + quad * 8]);
            const bfrag Va1 = *(const bfrag*)(&Vs[(16 + col) * VS_STRIDE + c2 * 32 + quad * 8]);
            Ot00 = __builtin_amdgcn_mfma_f32_16x16x32_bf16(Va0, P0.f, Ot00, 0, 0, 0);
            Ot10 = __builtin_amdgcn_mfma_f32_16x16x32_bf16(Va1, P0.f, Ot10, 0, 0, 0);
            Ot01 = __builtin_amdgcn_mfma_f32_16x16x32_bf16(Va0, P1.f, Ot01, 0, 0, 0);
            Ot11 = __builtin_amdgcn_mfma_f32_16x16x32_bf16(Va1, P1.f, Ot11, 0, 0, 0);
        }
        __syncthreads();
    }

    // store partials: O^T -> Opart[q][d]; l from Ot1 (d=24 row = quad 2, r=0)
    const size_t base0 = ((size_t)split * N_ + qbase0 + col) * 32;
    const size_t base1 = ((size_t)split * N_ + qbase1 + col) * 32;
    *(ffrag*)(&Opart[base0 + quad * 4]) = Ot00;
    *(ffrag*)(&Opart[base1 + quad * 4]) = Ot01;
    if (quad < 2) {
        *(ffrag*)(&Opart[base0 + 16 + quad * 4]) = Ot10;   // d 16..23
        *(ffrag*)(&Opart[base1 + 16 + quad * 4]) = Ot11;
    }
    if (quad == 2) {
        lpart[(size_t)split * N_ + qbase0 + col] = Ot10[0]; // d=24 = sum(P) = l
        lpart[(size_t)split * N_ + qbase1 + col] = Ot11[0];
    }
}

// ---------------- Kernel 3: combine + output projection ----------------
__global__ __launch_bounds__(256) void combine_kernel(
    const float* __restrict__ Opart, const float* __restrict__ lpart,
    const unsigned short* __restrict__ wOf, const float* __restrict__ bO,
    float* __restrict__ out, int nsp)
{
    __shared__ unsigned short Hs[64 * HS_STRIDE];

    const int tid = threadIdx.x;
    const int qb  = blockIdx.x * 64;
    {
        const int ql = tid >> 2;
        const int c8 = (tid & 3) * 8;     // dim chunk 0,8,16,24
        const int q  = qb + ql;
        float a[8] = {0.f, 0.f, 0.f, 0.f, 0.f, 0.f, 0.f, 0.f};
        if (c8 < 24) {                    // chunk 24..31 never written -> zeros
            for (int s = 0; s < nsp; ++s) {
                const float* p = &Opart[((size_t)s * N_ + q) * 32 + c8];
                const float4 u = *(const float4*)p;
                const float4 v = *(const float4*)(p + 4);
                a[0] += u.x; a[1] += u.y; a[2] += u.z; a[3] += u.w;
                a[4] += v.x; a[5] += v.y; a[6] += v.z; a[7] += v.w;
            }
        }
        float ls = 0.f;
        for (int s = 0; s < nsp; ++s) ls += lpart[(size_t)s * N_ + q];
        const float inv = 1.0f / ls;
        uint4 pk;
        pk.x = pack2(a[0] * inv, a[1] * inv);
        pk.y = pack2(a[2] * inv, a[3] * inv);
        pk.z = pack2(a[4] * inv, a[5] * inv);
        pk.w = pack2(a[6] * inv, a[7] * inv);
        *(uint4*)(&Hs[ql * HS_STRIDE + c8]) = pk;
    }
    __syncthreads();

    const int lane = tid & 63;
    const int w    = tid >> 6;
    const int col  = lane & 15;
    const int quad = lane >> 4;
    const bfrag Hf = *(const bfrag*)(&Hs[(w * 16 + col) * HS_STRIDE + quad * 8]);
    #pragma unroll
    for (int nt = 0; nt < 8; ++nt) {
        const bfrag Wo = *(const bfrag*)(wOf + (nt * 64 + lane) * 8);
        ffrag C = {0.f, 0.f, 0.f, 0.f};
        C = __builtin_amdgcn_mfma_f32_16x16x32_bf16(Hf, Wo, C, 0, 0, 0);
        const float bo = bO[nt * 16 + col];
        #pragma unroll
        for (int r = 0; r < 4; ++r)
            out[(size_t)(qb + w * 16 + quad * 4 + r) * 128 + nt * 16 + col] = C[r] + bo;
    }
}

extern "C" void kernel_launch(void* const* d_in, const int* in_sizes, int n_in,
                              void* d_out, int out_size, void* d_ws, size_t ws_size,
                              hipStream_t stream) {
    const float* x  = (const float*)d_in[0];
    const float* wQ = (const float*)d_in[1];
    const float* bQ = (const float*)d_in[2];
    const float* wK = (const float*)d_in[3];
    const float* bK = (const float*)d_in[4];
    const float* wV = (const float*)d_in[5];
    const float* bV = (const float*)d_in[6];
    const float* wO = (const float*)d_in[7];
    const float* bO = (const float*)d_in[8];
    float* out = (float*)d_out;

    unsigned short* ws16 = (unsigned short*)d_ws;
    unsigned short* Qbf = ws16;                                    // N*32 shorts
    unsigned short* Kbf = Qbf + (size_t)N_ * 32;                   // N*32
    unsigned short* Vt  = Kbf + (size_t)N_ * 32;                   // B*24*S
    unsigned short* Wf  = Vt + (size_t)B_ * 24 * S_;               // 10240
    unsigned short* wOf = Wf + 4 * 5 * 512;                        // 4096
    float* bqkv = (float*)(wOf + 8 * 512);                         // 80 fp32
    float* Opart = bqkv + 80;                                      // nsp*N*32 fp32
    const size_t baseBytes = (size_t)((char*)Opart - (char*)d_ws);

    int nsp = 4;
    while (nsp > 1) {
        const size_t need = baseBytes + (size_t)nsp * N_ * 32 * 4 + (size_t)nsp * N_ * 4;
        if (need <= ws_size) break;
        nsp >>= 1;
    }
    float* lpart = Opart + (size_t)nsp * N_ * 32;

    prep_kernel<<<8, 256, 0, stream>>>(wQ, bQ, wK, bK, wV, bV, wO, Wf, wOf, bqkv);
    proj_kernel<<<N_ / 64, 256, 0, stream>>>(x, Wf, bqkv, Qbf, Kbf, Vt);
    attn_kernel<<<dim3(N_ / 128, nsp), 256, 0, stream>>>(Qbf, Kbf, Vt, Opart, lpart);
    combine_kernel<<<N_ / 64, 256, 0, stream>>>(Opart, lpart, wOf, bO, out, nsp);
}

// Round 9
// 122.265 us; speedup vs baseline: 1.0240x; 1.0240x over previous
//
#include <hip/hip_runtime.h>
#include <hip/hip_fp16.h>

// MyEncoder: B=8, S=4096, E=128, D=24, fp32 in/out.
// out = softmax((xWq+bq)(xWk+bk)^T / sqrt(128)) (xWv+bv) Wo + bo
// bf16-MFMA pipeline: prep -> proj (QKV GEMM) -> attn (flash partials,
// K-split, transposed scores, in-register P, full-K PV, MFMA-computed l,
// 512-thread blocks) -> combine (sum fp16 partials + wO epilogue).
// Softmax without max-subtraction (scores tiny, shift-invariant) => K-split
// partials purely additive. exp2 with log2(e) folded into Q scale.

#define B_ 8
#define S_ 4096
#define E_ 128
#define D_ 24
#define N_ (B_ * S_)               // 32768 rows
#define SCALE 0.08838834764831845f // 1/sqrt(128)
#define LOG2E 1.4426950408889634f

#define TK 128                     // keys per LDS tile in attn
#define KS_STRIDE 40               // K_s row stride (shorts)
#define VS_STRIDE 136              // V_s row stride (shorts): 128 + 8 pad
#define HS_STRIDE 40               // H_s row stride in combine
#define XS_STRIDE 136              // x_s row stride (bf16) in proj
#define OS_STRIDE 84               // out_s row stride (fp32) in proj

typedef __attribute__((ext_vector_type(8))) short bfrag;   // 8 bf16 = 4 VGPR
typedef __attribute__((ext_vector_type(4))) float ffrag;   // 4 fp32 acc

__device__ inline unsigned short f2bf(float f) {           // RNE fp32->bf16
    unsigned int x = __builtin_bit_cast(unsigned int, f);
    return (unsigned short)((x + 0x7fffu + ((x >> 16) & 1u)) >> 16);
}
// round-half-up bf16 pair pack: 2 int-adds + v_perm (validated r5-r7 on HW)
__device__ inline unsigned int pack2h(float a, float b) {
    unsigned int ua = __builtin_bit_cast(unsigned int, a) + 0x8000u;
    unsigned int ub = __builtin_bit_cast(unsigned int, b) + 0x8000u;
    return __builtin_amdgcn_perm(ub, ua, 0x07060302);      // [a.hi16 | b.hi16]
}
// fp16 pair pack, RTZ, single v_cvt_pkrtz_f16_f32
__device__ inline unsigned int packh16(float a, float b) {
    return __builtin_bit_cast(unsigned int, __builtin_amdgcn_cvt_pkrtz(a, b));
}

// ---------------- Kernel 0: weight prep (8 blocks) ----------------
// Wf  [kt=4][nt=5][lane=64][j=8]: W[k][n], k=kt*32+quad*8+j, n=nt*16+(lane&15)
//     W = [wQ*SCALE*LOG2E | wK | wV | 0pad] (128 x 80)
// wOf [nt=8][lane=64][j=8]: wO[k][e], k=quad*8+j (zero for k>=24)
// bqkv[80] fp32 = [bQ*SCALE*LOG2E | bK | bV | 0]
__global__ __launch_bounds__(256) void prep_kernel(
    const float* __restrict__ wQ, const float* __restrict__ bQ,
    const float* __restrict__ wK, const float* __restrict__ bK,
    const float* __restrict__ wV, const float* __restrict__ bV,
    const float* __restrict__ wO,
    unsigned short* __restrict__ Wf, unsigned short* __restrict__ wOf,
    float* __restrict__ bqkv)
{
    const int gtid   = blockIdx.x * 256 + threadIdx.x;
    const int stride = gridDim.x * 256;
    const float qs = SCALE * LOG2E;
    for (int idx = gtid; idx < 4 * 5 * 512; idx += stride) {
        const int j    = idx & 7;
        const int lane = (idx >> 3) & 63;
        const int nt   = (idx >> 9) % 5;
        const int kt   = idx / 2560;
        const int n = nt * 16 + (lane & 15);
        const int k = kt * 32 + ((lane >> 4) << 3) + j;
        float v = 0.0f;
        if (n < 24)      v = wQ[k * 24 + n] * qs;
        else if (n < 48) v = wK[k * 24 + (n - 24)];
        else if (n < 72) v = wV[k * 24 + (n - 48)];
        Wf[idx] = f2bf(v);
    }
    for (int idx = gtid; idx < 8 * 512; idx += stride) {
        const int j    = idx & 7;
        const int lane = (idx >> 3) & 63;
        const int nt   = idx >> 9;
        const int k = ((lane >> 4) << 3) + j;
        const int e = nt * 16 + (lane & 15);
        wOf[idx] = (k < 24) ? f2bf(wO[k * 128 + e]) : (unsigned short)0;
    }
    if (gtid < 80) {
        float v = 0.0f;
        if (gtid < 24)      v = bQ[gtid] * qs;
        else if (gtid < 48) v = bK[gtid - 24];
        else if (gtid < 72) v = bV[gtid - 48];
        bqkv[gtid] = v;
    }
}

// ---------------- Kernel 1: QKV projection (MFMA) ----------------
__global__ __launch_bounds__(256) void proj_kernel(
    const float* __restrict__ x, const unsigned short* __restrict__ Wf,
    const float* __restrict__ bqkv,
    unsigned short* __restrict__ Qbf, unsigned short* __restrict__ Kbf,
    unsigned short* __restrict__ Vt)
{
    __shared__ float smem[64 * OS_STRIDE];          // 21504 B, dual-purpose
    unsigned short* xs = (unsigned short*)smem;     // [64][XS_STRIDE]
    float* os = smem;                               // [64][OS_STRIDE]

    const int tid  = threadIdx.x;
    const int lane = tid & 63;
    const int w    = tid >> 6;
    const int col  = lane & 15;
    const int quad = lane >> 4;
    const int rb   = blockIdx.x * 64;

    #pragma unroll
    for (int i = 0; i < 8; ++i) {
        const int idx = i * 256 + tid;
        const int row = idx >> 5, c4 = idx & 31;
        const float4 xv = *(const float4*)(x + (size_t)(rb + row) * 128 + c4 * 4);
        uint2 h;
        h.x = pack2h(xv.x, xv.y);
        h.y = pack2h(xv.z, xv.w);
        *(uint2*)(&xs[row * XS_STRIDE + c4 * 4]) = h;
    }

    bfrag Wfr[20];
    #pragma unroll
    for (int f = 0; f < 20; ++f)
        Wfr[f] = *(const bfrag*)(Wf + (f * 64 + lane) * 8);

    __syncthreads();

    ffrag acc[5];
    #pragma unroll
    for (int nt = 0; nt < 5; ++nt) acc[nt] = (ffrag){0.f, 0.f, 0.f, 0.f};

    #pragma unroll
    for (int kt = 0; kt < 4; ++kt) {
        const bfrag Af = *(const bfrag*)(&xs[(w * 16 + col) * XS_STRIDE + kt * 32 + quad * 8]);
        #pragma unroll
        for (int nt = 0; nt < 5; ++nt)
            acc[nt] = __builtin_amdgcn_mfma_f32_16x16x32_bf16(Af, Wfr[kt * 5 + nt], acc[nt], 0, 0, 0);
    }

    __syncthreads();

    #pragma unroll
    for (int nt = 0; nt < 5; ++nt) {
        const float bb = bqkv[nt * 16 + col];
        #pragma unroll
        for (int r = 0; r < 4; ++r)
            os[(w * 16 + quad * 4 + r) * OS_STRIDE + nt * 16 + col] = acc[nt][r] + bb;
    }
    __syncthreads();

    // Q (tid<128) / K (tid>=128): row-major bf16, cols padded to 32
    {
        const int half  = tid & 1;
        const int row   = (tid >> 1) & 63;
        const int isK   = tid >> 7;
        const int cbase = isK * 24;
        unsigned int pk[8];
        #pragma unroll
        for (int g = 0; g < 8; ++g) {
            const int c0 = half * 16 + g * 2;
            const float f0 = (c0     < 24) ? os[row * OS_STRIDE + cbase + c0]     : 0.0f;
            const float f1 = (c0 + 1 < 24) ? os[row * OS_STRIDE + cbase + c0 + 1] : 0.0f;
            pk[g] = pack2h(f0, f1);
        }
        unsigned short* dst = (isK ? Kbf : Qbf) + (size_t)(rb + row) * 32 + half * 16;
        *(uint4*)(dst)     = make_uint4(pk[0], pk[1], pk[2], pk[3]);
        *(uint4*)(dst + 8) = make_uint4(pk[4], pk[5], pk[6], pk[7]);
    }

    // Vt: transposed [b][d][s], 16B stores
    if (tid < 192) {
        const int d  = tid % 24;
        const int ch = tid / 24;
        unsigned int p[4];
        #pragma unroll
        for (int g = 0; g < 4; ++g) {
            const float f0 = os[(ch * 8 + g * 2 + 0) * OS_STRIDE + 48 + d];
            const float f1 = os[(ch * 8 + g * 2 + 1) * OS_STRIDE + 48 + d];
            p[g] = pack2h(f0, f1);
        }
        const int b = rb >> 12, s0 = rb & 4095;
        uint4* dst = (uint4*)(Vt + (((size_t)(b * 24 + d)) << 12) + s0 + ch * 8);
        *dst = make_uint4(p[0], p[1], p[2], p[3]);
    }
}

// ---------------- Kernel 2: flash attention partials ----------------
// Grid (N/128, KSP). 512 threads = 8 waves x 1 q-tile of 16 -> 128 q/block.
// K staged permuted: key k -> row (k&~31)+(((k>>2)&1)<<4)+(((k&31)>>3)<<2)+(k&3)
// so chunk 2*c2 gives keys quad*8+r, chunk 2*c2+1 gives quad*8+4+r -> one
// full K=32 P fragment per 32 keys. V natural order; V row d=24 = 1.0 so
// the PV MFMA computes l in Ot1's d=24 element. Staging/barriers amortized
// over 8 waves; 32-VGPR body keeps 8 waves/SIMD at 4 blocks/CU.
__global__ __launch_bounds__(512, 8) void attn_kernel(
    const unsigned short* __restrict__ Qbf, const unsigned short* __restrict__ Kbf,
    const unsigned short* __restrict__ Vt,
    __half* __restrict__ Opart, float* __restrict__ lpart)
{
    __shared__ unsigned short Ks[TK * KS_STRIDE];     // 10240 B
    __shared__ unsigned short Vs[32 * VS_STRIDE];     // 8704 B (rows 25-31 unused)

    const int tid    = threadIdx.x;
    const int lane   = tid & 63;
    const int w      = tid >> 6;                      // 0..7
    const int col    = lane & 15;
    const int quad   = lane >> 4;
    const int blk    = blockIdx.x;                    // 0..N/128-1
    const int split  = blockIdx.y;
    const int nsp    = gridDim.y;
    const int kchunk = S_ / nsp;
    const int b      = blk >> 5;                      // 32 blocks per batch
    const int qbase  = blk * 128 + w * 16;

    // ones row d=24 (written once; staging only touches rows 0..23)
    if (tid < 16)
        *(uint4*)(&Vs[24 * VS_STRIDE + tid * 8]) =
            make_uint4(0x3F803F80u, 0x3F803F80u, 0x3F803F80u, 0x3F803F80u);

    const bfrag Qf = *(const bfrag*)(Qbf + (size_t)(qbase + col) * 32 + quad * 8);

    ffrag Ot0 = {0.f, 0.f, 0.f, 0.f};   // O^T d = quad*4+r      (0..15)
    ffrag Ot1 = {0.f, 0.f, 0.f, 0.f};   // O^T d = 16+quad*4+r   (d=24 is l)

    const unsigned short* Kbase = Kbf + ((size_t)(b * 4096) + split * kchunk) * 32;
    const unsigned short* Vbase = Vt + (size_t)(b * 24) * 4096 + split * kchunk;

    __syncthreads();   // ones row visible

    for (int kb = 0; kb < kchunk; kb += TK) {
        // K tile: permuted rows, 128 keys x 32 bf16 (1 uint4 per thread)
        {
            const int key = tid >> 2, ch = tid & 3;
            const uint4 t4 = *(const uint4*)(Kbase + (size_t)(kb + key) * 32 + ch * 8);
            const int row = (key & ~31) + (((key >> 2) & 1) << 4)
                          + (((key & 31) >> 3) << 2) + (key & 3);
            *(uint4*)(&Ks[row * KS_STRIDE + ch * 8]) = t4;
        }
        // V tile: 24 d-rows x 128 keys, natural order
        if (tid < 384) {
            const int d = tid >> 4, ch = tid & 15;
            const uint4 t4 = *(const uint4*)(Vbase + (size_t)d * 4096 + kb + ch * 8);
            *(uint4*)(&Vs[d * VS_STRIDE + ch * 8]) = t4;
        }
        __syncthreads();

        #pragma unroll
        for (int c2 = 0; c2 < 4; ++c2) {
            const bfrag Kfe = *(const bfrag*)(&Ks[(c2 * 32 + col) * KS_STRIDE + quad * 8]);
            const bfrag Kfo = *(const bfrag*)(&Ks[(c2 * 32 + 16 + col) * KS_STRIDE + quad * 8]);
            ffrag Se = {0.f, 0.f, 0.f, 0.f};
            ffrag So = {0.f, 0.f, 0.f, 0.f};
            Se = __builtin_amdgcn_mfma_f32_16x16x32_bf16(Kfe, Qf, Se, 0, 0, 0);
            So = __builtin_amdgcn_mfma_f32_16x16x32_bf16(Kfo, Qf, So, 0, 0, 0);
            union { bfrag f; unsigned int u[4]; } P;
            P.u[0] = pack2h(__builtin_amdgcn_exp2f(Se[0]), __builtin_amdgcn_exp2f(Se[1]));
            P.u[1] = pack2h(__builtin_amdgcn_exp2f(Se[2]), __builtin_amdgcn_exp2f(Se[3]));
            P.u[2] = pack2h(__builtin_amdgcn_exp2f(So[0]), __builtin_amdgcn_exp2f(So[1]));
            P.u[3] = pack2h(__builtin_amdgcn_exp2f(So[2]), __builtin_amdgcn_exp2f(So[3]));
            const bfrag Va0 = *(const bfrag*)(&Vs[col * VS_STRIDE + c2 * 32 + quad * 8]);
            const bfrag Va1 = *(const bfrag*)(&Vs[(16 + col) * VS_STRIDE + c2 * 32 + quad * 8]);
            Ot0 = __builtin_amdgcn_mfma_f32_16x16x32_bf16(Va0, P.f, Ot0, 0, 0, 0);
            Ot1 = __builtin_amdgcn_mfma_f32_16x16x32_bf16(Va1, P.f, Ot1, 0, 0, 0);
        }
        __syncthreads();
    }

    // store fp16 partials: O^T -> Opart[q][d]; l from Ot1 d=24 (quad 2, r=0)
    const size_t base = ((size_t)split * N_ + qbase + col) * 32;
    {
        uint2 s0;
        s0.x = packh16(Ot0[0], Ot0[1]);
        s0.y = packh16(Ot0[2], Ot0[3]);
        *(uint2*)(Opart + base + quad * 4) = s0;
    }
    if (quad < 2) {
        uint2 s1;
        s1.x = packh16(Ot1[0], Ot1[1]);
        s1.y = packh16(Ot1[2], Ot1[3]);
        *(uint2*)(Opart + base + 16 + quad * 4) = s1;   // d 16..23
    }
    if (quad == 2)
        lpart[(size_t)split * N_ + qbase + col] = Ot1[0]; // d=24 = sum(P) = l
}

// ---------------- Kernel 3: combine + output projection ----------------
__global__ __launch_bounds__(256) void combine_kernel(
    const __half* __restrict__ Opart, const float* __restrict__ lpart,
    const unsigned short* __restrict__ wOf, const float* __restrict__ bO,
    float* __restrict__ out, int nsp)
{
    __shared__ unsigned short Hs[64 * HS_STRIDE];

    const int tid = threadIdx.x;
    const int qb  = blockIdx.x * 64;
    {
        const int ql = tid >> 2;
        const int c8 = (tid & 3) * 8;     // dim chunk 0,8,16,24
        const int q  = qb + ql;
        float a[8] = {0.f, 0.f, 0.f, 0.f, 0.f, 0.f, 0.f, 0.f};
        if (c8 < 24) {                    // chunk 24..31 never written -> zeros
            for (int s = 0; s < nsp; ++s) {
                const __half2* p2 = (const __half2*)(Opart + ((size_t)s * N_ + q) * 32 + c8);
                #pragma unroll
                for (int j = 0; j < 4; ++j) {
                    const float2 f = __half22float2(p2[j]);
                    a[2 * j]     += f.x;
                    a[2 * j + 1] += f.y;
                }
            }
        }
        float ls = 0.f;
        for (int s = 0; s < nsp; ++s) ls += lpart[(size_t)s * N_ + q];
        const float inv = 1.0f / ls;
        uint4 pk;
        pk.x = pack2h(a[0] * inv, a[1] * inv);
        pk.y = pack2h(a[2] * inv, a[3] * inv);
        pk.z = pack2h(a[4] * inv, a[5] * inv);
        pk.w = pack2h(a[6] * inv, a[7] * inv);
        *(uint4*)(&Hs[ql * HS_STRIDE + c8]) = pk;
    }
    __syncthreads();

    const int lane = tid & 63;
    const int w    = tid >> 6;
    const int col  = lane & 15;
    const int quad = lane >> 4;
    const bfrag Hf = *(const bfrag*)(&Hs[(w * 16 + col) * HS_STRIDE + quad * 8]);
    #pragma unroll
    for (int nt = 0; nt < 8; ++nt) {
        const bfrag Wo = *(const bfrag*)(wOf + (nt * 64 + lane) * 8);
        ffrag C = {0.f, 0.f, 0.f, 0.f};
        C = __builtin_amdgcn_mfma_f32_16x16x32_bf16(Hf, Wo, C, 0, 0, 0);
        const float bo = bO[nt * 16 + col];
        #pragma unroll
        for (int r = 0; r < 4; ++r)
            out[(size_t)(qb + w * 16 + quad * 4 + r) * 128 + nt * 16 + col] = C[r] + bo;
    }
}

extern "C" void kernel_launch(void* const* d_in, const int* in_sizes, int n_in,
                              void* d_out, int out_size, void* d_ws, size_t ws_size,
                              hipStream_t stream) {
    const float* x  = (const float*)d_in[0];
    const float* wQ = (const float*)d_in[1];
    const float* bQ = (const float*)d_in[2];
    const float* wK = (const float*)d_in[3];
    const float* bK = (const float*)d_in[4];
    const float* wV = (const float*)d_in[5];
    const float* bV = (const float*)d_in[6];
    const float* wO = (const float*)d_in[7];
    const float* bO = (const float*)d_in[8];
    float* out = (float*)d_out;

    unsigned short* ws16 = (unsigned short*)d_ws;
    unsigned short* Qbf = ws16;                                    // N*32 shorts
    unsigned short* Kbf = Qbf + (size_t)N_ * 32;                   // N*32
    unsigned short* Vt  = Kbf + (size_t)N_ * 32;                   // B*24*S
    unsigned short* Wf  = Vt + (size_t)B_ * 24 * S_;               // 10240
    unsigned short* wOf = Wf + 4 * 5 * 512;                        // 4096
    float* bqkv = (float*)(wOf + 8 * 512);                         // 80 fp32
    __half* Opart = (__half*)(bqkv + 80);                          // nsp*N*32 fp16
    const size_t baseBytes = (size_t)((char*)Opart - (char*)d_ws);

    int nsp = 4;
    while (nsp > 1) {
        const size_t need = baseBytes + (size_t)nsp * N_ * 32 * 2 + (size_t)nsp * N_ * 4;
        if (need <= ws_size) break;
        nsp >>= 1;
    }
    float* lpart = (float*)(Opart + (size_t)nsp * N_ * 32);

    prep_kernel<<<8, 256, 0, stream>>>(wQ, bQ, wK, bK, wV, bV, wO, Wf, wOf, bqkv);
    proj_kernel<<<N_ / 64, 256, 0, stream>>>(x, Wf, bqkv, Qbf, Kbf, Vt);
    attn_kernel<<<dim3(N_ / 128, nsp), 512, 0, stream>>>(Qbf, Kbf, Vt, Opart, lpart);
    combine_kernel<<<N_ / 64, 256, 0, stream>>>(Opart, lpart, wOf, bO, out, nsp);
}